// Round 2
// baseline (1545.005 us; speedup 1.0000x reference)
//
#include <hip/hip_runtime.h>
#include <hip/hip_cooperative_groups.h>
#include <cmath>

namespace cg = cooperative_groups;

// Problem constants: T=128, N=64, D=512, H=512
#define TT 128
#define NN 64
#define DD 512
#define HH 512
#define GG 1536  // 3*H

// ---- workspace layout (bytes) ----
#define META_OFF   0         // meta[0]=max depth, meta[1]=zero-row count
#define ROFF_OFF   256       // int roundOff[130]
#define ZROWS_OFF  4096      // int zRows[8192]
#define ROWOUT_OFF 36864     // int rowOut[8192]
#define ROWHS_OFF  69632     // int rowHsrc[8192]  (>=8192 -> hxs row (v-8192))
#define GI_OFF     1048576   // float gi[8192][1536], 50.3 MB
#define WS_NEEDED  (GI_OFF + (size_t)TT * NN * GG * 4)

// ---------------------------------------------------------------------------
// Depth classification. Row (t,n): h_in = mask[t]*out[t-1] (hxs at t=0).
// mask==0  -> depth 0, h_in = 0 (pure elementwise "zero-row").
// t==0, mask!=0 -> depth 0 GEMM row, h source = hxs[n].
// else -> depth = depth(t-1)+1, h source = out[(t-1)*64+n].
// Rows are counting-sorted by depth into rowOut/rowHsrc; zero rows in zRows.
// ---------------------------------------------------------------------------
__global__ void build_rounds(const float* __restrict__ masks, int* __restrict__ meta,
                             int* __restrict__ roundOff, int* __restrict__ zRows,
                             int* __restrict__ rowOut, int* __restrict__ rowHsrc) {
  __shared__ int cnt[129];
  __shared__ int cur[129];
  __shared__ int zcur;
  const int tid = threadIdx.x;  // 128 threads
  for (int i = tid; i < 129; i += 128) cnt[i] = 0;
  if (tid == 0) zcur = 0;
  __syncthreads();
  if (tid < NN) {
    const int n = tid;
    int depth = 0;
    for (int t = 0; t < TT; ++t) {
      if (masks[t * NN + n] == 0.0f) {
        depth = 0;
        atomicAdd(&zcur, 1);
      } else {
        depth = (t == 0) ? 0 : depth + 1;
        atomicAdd(&cnt[depth], 1);
      }
    }
  }
  __syncthreads();
  if (tid == 0) {
    int acc = 0, maxs = -1;
    for (int s = 0; s < 129; ++s) {
      roundOff[s] = acc;
      cur[s] = acc;
      if (cnt[s] > 0) maxs = s;
      acc += cnt[s];
    }
    roundOff[129] = acc;
    meta[0] = maxs;
    meta[1] = zcur;
    zcur = 0;
  }
  __syncthreads();
  if (tid < NN) {
    const int n = tid;
    int depth = 0;
    for (int t = 0; t < TT; ++t) {
      if (masks[t * NN + n] == 0.0f) {
        depth = 0;
        const int p = atomicAdd(&zcur, 1);
        zRows[p] = t * NN + n;
      } else {
        depth = (t == 0) ? 0 : depth + 1;
        const int p = atomicAdd(&cur[depth], 1);
        rowOut[p] = t * NN + n;
        rowHsrc[p] = (t == 0) ? (8192 + n) : ((t - 1) * NN + n);
      }
    }
  }
}

// ---------------------------------------------------------------------------
// gi = x @ w_ih^T + b_ih   (fp32, 8192x1536, K=512). 128x128 tile, 8x8/thread.
// ---------------------------------------------------------------------------
__global__ __launch_bounds__(256, 4) void gemm_gi(const float* __restrict__ x,
                                                  const float* __restrict__ w,
                                                  const float* __restrict__ bias,
                                                  float* __restrict__ gi) {
  __shared__ __align__(16) float As[32][132];
  __shared__ __align__(16) float Bs[32][132];
  const int tid = threadIdx.x;
  const int m0 = blockIdx.y * 128;
  const int n0 = blockIdx.x * 128;
  const int tx = tid & 15;
  const int ty = tid >> 4;
  float acc[8][8] = {};
  for (int k0 = 0; k0 < DD; k0 += 32) {
#pragma unroll
    for (int i = 0; i < 4; ++i) {
      const int q = tid + i * 256;
      const int row = q >> 3;
      const int kf = (q & 7) << 2;
      const float4 va = *(const float4*)&x[(size_t)(m0 + row) * DD + k0 + kf];
      As[kf + 0][row] = va.x; As[kf + 1][row] = va.y;
      As[kf + 2][row] = va.z; As[kf + 3][row] = va.w;
      const float4 vb = *(const float4*)&w[(size_t)(n0 + row) * DD + k0 + kf];
      Bs[kf + 0][row] = vb.x; Bs[kf + 1][row] = vb.y;
      Bs[kf + 2][row] = vb.z; Bs[kf + 3][row] = vb.w;
    }
    __syncthreads();
#pragma unroll
    for (int k = 0; k < 32; ++k) {
      float a[8], b[8];
      ((float4*)a)[0] = *(const float4*)&As[k][ty * 8];
      ((float4*)a)[1] = *(const float4*)&As[k][ty * 8 + 4];
      ((float4*)b)[0] = *(const float4*)&Bs[k][tx * 8];
      ((float4*)b)[1] = *(const float4*)&Bs[k][tx * 8 + 4];
#pragma unroll
      for (int i = 0; i < 8; ++i)
#pragma unroll
        for (int j = 0; j < 8; ++j) acc[i][j] = fmaf(a[i], b[j], acc[i][j]);
    }
    __syncthreads();
  }
  float bs[8];
  ((float4*)bs)[0] = *(const float4*)&bias[n0 + tx * 8];
  ((float4*)bs)[1] = *(const float4*)&bias[n0 + tx * 8 + 4];
#pragma unroll
  for (int i = 0; i < 8; ++i) {
    const int row = m0 + ty * 8 + i;
    float4 o0 = make_float4(acc[i][0] + bs[0], acc[i][1] + bs[1],
                            acc[i][2] + bs[2], acc[i][3] + bs[3]);
    float4 o1 = make_float4(acc[i][4] + bs[4], acc[i][5] + bs[5],
                            acc[i][6] + bs[6], acc[i][7] + bs[7]);
    *(float4*)&gi[(size_t)row * GG + n0 + tx * 8] = o0;
    *(float4*)&gi[(size_t)row * GG + n0 + tx * 8 + 4] = o1;
  }
}

// ---------------------------------------------------------------------------
// Cooperative round-synchronized recurrence.
// Grid = 256 blocks (32 colgroups x 8 rowgroups) x 512 threads, 1 block/CU.
// Block owns h-cols [cg*16, cg*16+16): its 48 w_hh rows (3 gates x 16 cols)
// stay LDS-resident (99 KB) for the whole kernel. Per round, its rowgroup's
// slice of depth-s rows is processed in 128-row tiles: h staged in
// double-buffered 32-wide k-chunks, 12 FMA-outputs/thread (4 rows x 3 gates),
// fused sigmoid/tanh epilogue, then __threadfence + grid.sync.
// ---------------------------------------------------------------------------
#define NGC 32
#define GCW 16
#define NRG 8
#define RT  128
#define KT  32
#define WSTR 516  // 512 + 4 pad (breaks 2KB bank stride)
#define HSTR 36   // 32 + 4 pad

__global__ __launch_bounds__(512) void gru_rounds(
    const float* __restrict__ gi, const float* __restrict__ w_hh,
    const float* __restrict__ b_hh, const float* __restrict__ hxs,
    const float* __restrict__ hxs_1, float* __restrict__ out,
    const int* __restrict__ meta, const int* __restrict__ roundOff,
    const int* __restrict__ zRows, const int* __restrict__ rowOut,
    const int* __restrict__ rowHsrc) {
  __shared__ __align__(16) float wS[3 * GCW * WSTR];   // 99072 B
  __shared__ __align__(16) float hS[2 * RT * HSTR];    // 36864 B
  __shared__ const float* s_hbase[RT];
  __shared__ int s_orow[RT];

  const int tid = threadIdx.x;
  const int bid = blockIdx.x;
  const int cgrp = bid & (NGC - 1);
  const int rg = bid >> 5;
  const int wv = tid >> 6;      // wave 0..7
  const int ln = tid & 63;
  const int tc = ln & 15;       // col-lane
  const int rsub = ln >> 4;     // 0..3
  const int lrbase = wv * 16 + rsub * 4;  // this thread's 4 tile-rows
  const int col = cgrp * GCW + tc;

  // ---- load the block's weight slice into LDS (once) ----
  {
    const float* src = w_hh;  // rows g*512 + cgrp*16 + r
    for (int q = tid; q < 3 * GCW * 128; q += 512) {  // float4 units
      const int gr = q >> 7;          // 0..47 (gate*16 + r)
      const int p = q & 127;
      const int g = gr >> 4, r = gr & 15;
      const float4 v =
          *(const float4*)&src[((size_t)(g * 512 + cgrp * GCW + r)) * 512 + p * 4];
      *(float4*)&wS[(g * GCW + r) * WSTR + p * 4] = v;
    }
  }
  const float bhr = b_hh[col], bhz = b_hh[512 + col], bhn = b_hh[1024 + col];
  __syncthreads();

  cg::grid_group grid = cg::this_grid();
  const int gtid = bid * 512 + tid;
  const int gnt = gridDim.x * 512;

  // ---- depth-0 zero-rows: h_in = 0 -> pure elementwise ----
  const int zcount = meta[1];
  for (int idx = gtid; idx < zcount * 512; idx += gnt) {
    const int zr = zRows[idx >> 9];
    const int c = idx & 511;
    const float* g = gi + (size_t)zr * GG + c;
    const float r = 1.0f / (1.0f + expf(-(g[0] + b_hh[c])));
    const float z = 1.0f / (1.0f + expf(-(g[512] + b_hh[512 + c])));
    const float nc = tanhf(g[1024] + r * b_hh[1024 + c]);
    out[(size_t)zr * HH + c] = (1.0f - z) * nc;
  }

  // ---- rounds ----
  const int maxs = meta[0];
  for (int s = 0; s <= maxs; ++s) {
    const int base = roundOff[s];
    const int cnt = roundOff[s + 1] - base;
    const int chunk = (cnt + NRG - 1) / NRG;
    const int rowStart = rg * chunk;
    int myCnt = cnt - rowStart;
    myCnt = myCnt < 0 ? 0 : (myCnt > chunk ? chunk : myCnt);

    for (int t0 = 0; t0 < myCnt; t0 += RT) {
      const int rows = min(RT, myCnt - t0);
      __syncthreads();  // previous tile's s_hbase/epilogue reads done
      for (int r = tid; r < RT; r += 512) {
        if (r < rows) {
          const int gidx = base + rowStart + t0 + r;
          s_orow[r] = rowOut[gidx];
          const int hs = rowHsrc[gidx];
          s_hbase[r] = (hs >= 8192) ? (hxs + (size_t)(hs - 8192) * HH)
                                    : (out + (size_t)hs * HH);
        } else {
          s_orow[r] = -1;
          s_hbase[r] = hxs;  // valid dummy
        }
      }
      __syncthreads();

      float acc[4][3];
#pragma unroll
      for (int j = 0; j < 4; ++j)
#pragma unroll
        for (int g2 = 0; g2 < 3; ++g2) acc[j][g2] = 0.0f;

      // staging lanes: 8 threads per row, float4 each (row = q>>3, k = (q&7)*4)
      const int sr0 = tid >> 3, sk0 = (tid & 7) * 4;
      const int sr1 = (tid + 512) >> 3, sk1 = ((tid + 512) & 7) * 4;
      float4 st0, st1;
      // chunk 0: load + write; chunk 1: load
      st0 = *(const float4*)(s_hbase[sr0] + sk0);
      st1 = *(const float4*)(s_hbase[sr1] + sk1);
      *(float4*)&hS[sr0 * HSTR + sk0] = st0;
      *(float4*)&hS[sr1 * HSTR + sk1] = st1;
      st0 = *(const float4*)(s_hbase[sr0] + KT + sk0);
      st1 = *(const float4*)(s_hbase[sr1] + KT + sk1);
      __syncthreads();

      const bool rowAct = (lrbase < rows);
      for (int c = 0; c < 16; ++c) {
        if (rowAct) {
          const float* hbuf = hS + (c & 1) * RT * HSTR + lrbase * HSTR;
          const float* wbuf = wS + tc * WSTR + c * KT;
#pragma unroll
          for (int kk = 0; kk < KT; kk += 4) {
            const float4 w0 = *(const float4*)(wbuf + kk);
            const float4 w1 = *(const float4*)(wbuf + GCW * WSTR + kk);
            const float4 w2 = *(const float4*)(wbuf + 2 * GCW * WSTR + kk);
#pragma unroll
            for (int j = 0; j < 4; ++j) {
              const float4 hv = *(const float4*)(hbuf + j * HSTR + kk);
              acc[j][0] = fmaf(w0.x, hv.x, acc[j][0]);
              acc[j][0] = fmaf(w0.y, hv.y, acc[j][0]);
              acc[j][0] = fmaf(w0.z, hv.z, acc[j][0]);
              acc[j][0] = fmaf(w0.w, hv.w, acc[j][0]);
              acc[j][1] = fmaf(w1.x, hv.x, acc[j][1]);
              acc[j][1] = fmaf(w1.y, hv.y, acc[j][1]);
              acc[j][1] = fmaf(w1.z, hv.z, acc[j][1]);
              acc[j][1] = fmaf(w1.w, hv.w, acc[j][1]);
              acc[j][2] = fmaf(w2.x, hv.x, acc[j][2]);
              acc[j][2] = fmaf(w2.y, hv.y, acc[j][2]);
              acc[j][2] = fmaf(w2.z, hv.z, acc[j][2]);
              acc[j][2] = fmaf(w2.w, hv.w, acc[j][2]);
            }
          }
        }
        if (c + 1 < 16) {  // write staged regs for chunk c+1
          float* hb = hS + ((c + 1) & 1) * RT * HSTR;
          *(float4*)&hb[sr0 * HSTR + sk0] = st0;
          *(float4*)&hb[sr1 * HSTR + sk1] = st1;
        }
        if (c + 2 < 16) {  // prefetch chunk c+2
          st0 = *(const float4*)(s_hbase[sr0] + (c + 2) * KT + sk0);
          st1 = *(const float4*)(s_hbase[sr1] + (c + 2) * KT + sk1);
        }
        __syncthreads();
      }

      // fused gate epilogue
#pragma unroll
      for (int j = 0; j < 4; ++j) {
        const int lr = lrbase + j;
        if (lr < rows) {
          const int orow = s_orow[lr];
          const float* gp = gi + (size_t)orow * GG + col;
          const float gr = gp[0], gz = gp[512], gn = gp[1024];
          const float r = 1.0f / (1.0f + expf(-(gr + acc[j][0] + bhr)));
          const float z = 1.0f / (1.0f + expf(-(gz + acc[j][1] + bhz)));
          const float hold = s_hbase[lr][col];
          const float nc = tanhf(gn + r * (acc[j][2] + bhn));
          out[(size_t)orow * HH + col] = (1.0f - z) * nc + z * hold;
        }
      }
    }
    __threadfence();
    grid.sync();
  }

  // ---- tail: h_last = out rows 8128..8191; then hxs_1 passthrough ----
  for (int i = gtid; i < 16384; i += gnt) {
    float4 v;
    if (i < 8192)
      v = ((const float4*)out)[1040384 + i];  // 8128*512/4
    else
      v = ((const float4*)hxs_1)[i - 8192];
    ((float4*)out)[1048576 + i] = v;
  }
}

extern "C" void kernel_launch(void* const* d_in, const int* in_sizes, int n_in,
                              void* d_out, int out_size, void* d_ws, size_t ws_size,
                              hipStream_t stream) {
  const float* x     = (const float*)d_in[0];
  const float* hxs   = (const float*)d_in[1];
  const float* hxs_1 = (const float*)d_in[2];
  const float* masks = (const float*)d_in[3];
  const float* w_ih  = (const float*)d_in[4];
  const float* w_hh  = (const float*)d_in[5];
  const float* b_ih  = (const float*)d_in[6];
  const float* b_hh  = (const float*)d_in[7];
  float* out = (float*)d_out;
  char* ws = (char*)d_ws;
  if (ws_size < WS_NEEDED) return;

  int* meta     = (int*)(ws + META_OFF);
  int* roundOff = (int*)(ws + ROFF_OFF);
  int* zRows    = (int*)(ws + ZROWS_OFF);
  int* rowOut   = (int*)(ws + ROWOUT_OFF);
  int* rowHsrc  = (int*)(ws + ROWHS_OFF);
  float* gi     = (float*)(ws + GI_OFF);

  build_rounds<<<1, 128, 0, stream>>>(masks, meta, roundOff, zRows, rowOut, rowHsrc);
  gemm_gi<<<dim3(12, 64), 256, 0, stream>>>(x, w_ih, b_ih, gi);

  const float* gi_c = gi;
  void* args[] = {(void*)&gi_c,  (void*)&w_hh,    (void*)&b_hh,  (void*)&hxs,
                  (void*)&hxs_1, (void*)&out,     (void*)&meta,  (void*)&roundOff,
                  (void*)&zRows, (void*)&rowOut,  (void*)&rowHsrc};
  hipLaunchCooperativeKernel((const void*)gru_rounds, dim3(256), dim3(512), args, 0,
                             stream);
}

// Round 3
// 1129.554 us; speedup vs baseline: 1.3678x; 1.3678x over previous
//
#include <hip/hip_runtime.h>
#include <cmath>

// Problem constants: T=128, N=64, D=512, H=512
#define TT 128
#define NN 64
#define DD 512
#define HH 512
#define GG 1536  // 3*H
#define WW 8     // segments per batch
#define GQ 4     // blocks (col-quarters) per batch

// ---- workspace layout (bytes) ----
// meta[0]=claim ctr, meta[1]=nTasks, meta[2]=headCnt, meta[3]=nBatches
#define META_OFF 0
#define CTR_OFF  4096      // int ctr[512*16]  (one counter per 64B line)
#define SEG_OFF  40960     // int4 segs[512*8]
#define ZR_OFF   131072    // int zRows[8192]
#define GI_OFF   4194304   // float gi[8192][1536], 50.3 MB
#define WS_NEEDED (GI_OFF + (size_t)TT * NN * GG * 4)

// ---------------------------------------------------------------------------
// Chain builder. Row (t,n): h_in = mask*h_prev. mask==0 rows are "heads"
// (h_in=0, pure elementwise). Maximal runs of mask==1 rows form chains; a
// chain's step-s h comes from out[(t_first-1+s)*64+n] (the head's output or
// the chain's own previous output), or hxs[n] when t_first==0 (seeded).
// Chains are counting-sorted by length (desc) and grouped into batches of 8;
// each batch is executed by 4 cooperating blocks (col-quarters).
// ---------------------------------------------------------------------------
__global__ void build_chains(const float* __restrict__ masks, int* __restrict__ meta,
                             int* __restrict__ ctr, int4* __restrict__ segs,
                             int* __restrict__ zRows) {
  __shared__ int hist[129];
  __shared__ int offs[129];
  __shared__ int zc;
  __shared__ int nsegS;
  const int tid = threadIdx.x;  // 128
  for (int i = tid; i < 129; i += 128) hist[i] = 0;
  for (int i = tid; i < 512 * 16; i += 128) ctr[i] = 0;
  if (tid == 0) zc = 0;
  __syncthreads();
  if (tid < NN) {
    const int n = tid;
    int run = 0;
    for (int t = 0; t < TT; ++t) {
      const bool m = masks[t * NN + n] != 0.0f;
      if (m) ++run;
      if (!m) {
        atomicAdd(&zc, 1);
        if (run > 0) { atomicAdd(&hist[run], 1); run = 0; }
      } else if (t == TT - 1) {
        atomicAdd(&hist[run], 1);
      }
    }
  }
  __syncthreads();
  if (tid == 0) {
    int acc = 0;
    for (int l = 128; l >= 1; --l) { offs[l] = acc; acc += hist[l]; }
    nsegS = acc;
    meta[2] = zc;
    zc = 0;
  }
  __syncthreads();
  if (tid < NN) {
    const int n = tid;
    int run = 0, tf = 0;
    for (int t = 0; t < TT; ++t) {
      const bool m = masks[t * NN + n] != 0.0f;
      if (m) { if (run == 0) tf = t; ++run; }
      if (!m) {
        const int p = atomicAdd(&zc, 1);
        zRows[p] = t * NN + n;
        if (run > 0) {
          const int pp = atomicAdd(&offs[run], 1);
          segs[pp] = make_int4(n, tf, run, 0);
          run = 0;
        }
      } else if (t == TT - 1) {
        const int pp = atomicAdd(&offs[run], 1);
        segs[pp] = make_int4(n, tf, run, 0);
      }
    }
  }
  __syncthreads();
  const int nseg = nsegS;
  const int nB = (nseg + WW - 1) / WW;
  for (int i = nseg + tid; i < nB * WW; i += 128) segs[i] = make_int4(0, 1, 0, 0);
  if (tid == 0) { meta[0] = 0; meta[1] = nB * GQ; meta[3] = nB; }
}

// ---------------------------------------------------------------------------
// gi = x @ w_ih^T + b_ih   (fp32, 8192x1536, K=512). 128x128 tile, 8x8/thread.
// ---------------------------------------------------------------------------
__global__ __launch_bounds__(256, 4) void gemm_gi(const float* __restrict__ x,
                                                  const float* __restrict__ w,
                                                  const float* __restrict__ bias,
                                                  float* __restrict__ gi) {
  __shared__ __align__(16) float As[32][132];
  __shared__ __align__(16) float Bs[32][132];
  const int tid = threadIdx.x;
  const int m0 = blockIdx.y * 128;
  const int n0 = blockIdx.x * 128;
  const int tx = tid & 15;
  const int ty = tid >> 4;
  float acc[8][8] = {};
  for (int k0 = 0; k0 < DD; k0 += 32) {
#pragma unroll
    for (int i = 0; i < 4; ++i) {
      const int q = tid + i * 256;
      const int row = q >> 3;
      const int kf = (q & 7) << 2;
      const float4 va = *(const float4*)&x[(size_t)(m0 + row) * DD + k0 + kf];
      As[kf + 0][row] = va.x; As[kf + 1][row] = va.y;
      As[kf + 2][row] = va.z; As[kf + 3][row] = va.w;
      const float4 vb = *(const float4*)&w[(size_t)(n0 + row) * DD + k0 + kf];
      Bs[kf + 0][row] = vb.x; Bs[kf + 1][row] = vb.y;
      Bs[kf + 2][row] = vb.z; Bs[kf + 3][row] = vb.w;
    }
    __syncthreads();
#pragma unroll
    for (int k = 0; k < 32; ++k) {
      float a[8], b[8];
      ((float4*)a)[0] = *(const float4*)&As[k][ty * 8];
      ((float4*)a)[1] = *(const float4*)&As[k][ty * 8 + 4];
      ((float4*)b)[0] = *(const float4*)&Bs[k][tx * 8];
      ((float4*)b)[1] = *(const float4*)&Bs[k][tx * 8 + 4];
#pragma unroll
      for (int i = 0; i < 8; ++i)
#pragma unroll
        for (int j = 0; j < 8; ++j) acc[i][j] = fmaf(a[i], b[j], acc[i][j]);
    }
    __syncthreads();
  }
  float bs[8];
  ((float4*)bs)[0] = *(const float4*)&bias[n0 + tx * 8];
  ((float4*)bs)[1] = *(const float4*)&bias[n0 + tx * 8 + 4];
#pragma unroll
  for (int i = 0; i < 8; ++i) {
    const int row = m0 + ty * 8 + i;
    float4 o0 = make_float4(acc[i][0] + bs[0], acc[i][1] + bs[1],
                            acc[i][2] + bs[2], acc[i][3] + bs[3]);
    float4 o1 = make_float4(acc[i][4] + bs[4], acc[i][5] + bs[5],
                            acc[i][6] + bs[6], acc[i][7] + bs[7]);
    *(float4*)&gi[(size_t)row * GG + n0 + tx * 8] = o0;
    *(float4*)&gi[(size_t)row * GG + n0 + tx * 8 + 4] = o1;
  }
}

// ---------------------------------------------------------------------------
// Head rows (h_in = 0): pure elementwise gates. gh = b_hh.
// ---------------------------------------------------------------------------
__global__ void heads_ew(const float* __restrict__ gi, const float* __restrict__ b_hh,
                         const int* __restrict__ meta, const int* __restrict__ zRows,
                         float* __restrict__ out) {
  const int total = meta[2] * HH;
  for (int idx = blockIdx.x * blockDim.x + threadIdx.x; idx < total;
       idx += gridDim.x * blockDim.x) {
    const int zr = zRows[idx >> 9];
    const int c = idx & 511;
    const float* g = gi + (size_t)zr * GG + c;
    const float r = 1.0f / (1.0f + expf(-(g[0] + b_hh[c])));
    const float z = 1.0f / (1.0f + expf(-(g[512] + b_hh[512 + c])));
    const float nc = tanhf(g[1024] + r * b_hh[1024 + c]);
    out[(size_t)zr * HH + c] = (1.0f - z) * nc;
  }
}

// ---------------------------------------------------------------------------
// Chain kernel. Persistent blocks claim tasks (batch, col-quarter) in prefix
// order: task = atomicAdd; batch=task/4, g=task%4. Block g streams 384 w_hh
// rows (cols [g*128,(g+1)*128) x 3 gates) from L2 each step (0.75 MB) and
// computes those 128 h-cols for 8 segments. Per-step cross-block sync via
// ctr[batch]: release-add after writing out rows, acquire-spin before
// reading partners' columns. Thread map: cc=tid&127 (col), q=tid>>7
// (k-quarter, 128 k each); partials reduced through LDS into the epilogue.
// ---------------------------------------------------------------------------
__global__ __launch_bounds__(512) void gru_chains(
    const float* __restrict__ gi, const float* __restrict__ w_hh,
    const float* __restrict__ b_hh, const float* __restrict__ hxs,
    float* __restrict__ out, int* __restrict__ meta, int* __restrict__ ctr,
    const int4* __restrict__ segs) {
  __shared__ __align__(16) float hS[WW][520];       // 16.6 KB staged h rows
  __shared__ __align__(16) float red[3 * WW][516];  // 49.5 KB k-partials
  __shared__ int4 sseg[WW];
  __shared__ int sTask;

  const int tid = threadIdx.x;
  const int cc = tid & 127;   // output column within quarter
  const int q = tid >> 7;     // k-quarter 0..3
  const int nTasks = meta[1];

  while (true) {
    if (tid == 0) sTask = atomicAdd(&meta[0], 1);
    __syncthreads();
    const int task = sTask;
    if (task >= nTasks) break;
    const int b = task >> 2;
    const int gq = task & 3;
    const int cb = gq * 128;
    if (tid < WW) sseg[tid] = segs[b * WW + tid];
    __syncthreads();
    const int maxlen = sseg[0].z;  // sorted desc -> first is longest
    const int col = cb + cc;
    const float bhr = b_hh[col];
    const float bhz = b_hh[512 + col];
    const float bhn = b_hh[1024 + col];
    const float* w0 = w_hh + (size_t)(col) * DD + q * 128;
    const float* w1 = w_hh + (size_t)(512 + col) * DD + q * 128;
    const float* w2 = w_hh + (size_t)(1024 + col) * DD + q * 128;

    for (int s = 0; s < maxlen; ++s) {
      if (s > 0) {
        if (tid == 0) {
          while (__hip_atomic_load(&ctr[b * 16], __ATOMIC_ACQUIRE,
                                   __HIP_MEMORY_SCOPE_AGENT) < GQ * s) {}
        }
        __syncthreads();
        __threadfence();
      }
      // ---- stage the 8 h rows (512 cols each) into LDS ----
      {
        const int j = tid >> 6, l = tid & 63;
        const int4 sg = sseg[j];
        const int r = sg.y - 1 + s;
        const bool act = (s < sg.z);
        const float* hp = act ? ((r >= 0) ? out + (size_t)(r * NN + sg.x) * HH
                                          : hxs + (size_t)sg.x * HH)
                              : out;  // safe dummy
        const float4 v0 = *(const float4*)(hp + l * 8);
        const float4 v1 = *(const float4*)(hp + l * 8 + 4);
        *(float4*)&hS[j][l * 8] = v0;
        *(float4*)&hS[j][l * 8 + 4] = v1;
      }
      __syncthreads();

      // ---- k-loop: 128 k per thread, 3 gates x 8 rows ----
      float acc0[WW], acc1[WW], acc2[WW];
#pragma unroll
      for (int j = 0; j < WW; ++j) { acc0[j] = 0.f; acc1[j] = 0.f; acc2[j] = 0.f; }
#pragma unroll 2
      for (int k = 0; k < 128; k += 4) {
        const float4 a0 = *(const float4*)(w0 + k);
        const float4 a1 = *(const float4*)(w1 + k);
        const float4 a2 = *(const float4*)(w2 + k);
#pragma unroll
        for (int j = 0; j < WW; ++j) {
          const float4 hv = *(const float4*)&hS[j][q * 128 + k];
          acc0[j] = fmaf(a0.x, hv.x, acc0[j]);
          acc0[j] = fmaf(a0.y, hv.y, acc0[j]);
          acc0[j] = fmaf(a0.z, hv.z, acc0[j]);
          acc0[j] = fmaf(a0.w, hv.w, acc0[j]);
          acc1[j] = fmaf(a1.x, hv.x, acc1[j]);
          acc1[j] = fmaf(a1.y, hv.y, acc1[j]);
          acc1[j] = fmaf(a1.z, hv.z, acc1[j]);
          acc1[j] = fmaf(a1.w, hv.w, acc1[j]);
          acc2[j] = fmaf(a2.x, hv.x, acc2[j]);
          acc2[j] = fmaf(a2.y, hv.y, acc2[j]);
          acc2[j] = fmaf(a2.z, hv.z, acc2[j]);
          acc2[j] = fmaf(a2.w, hv.w, acc2[j]);
        }
      }
      // ---- cross-quarter reduce via LDS ----
#pragma unroll
      for (int j = 0; j < WW; ++j) {
        red[0 * WW + j][cc * 4 + q] = acc0[j];
        red[1 * WW + j][cc * 4 + q] = acc1[j];
        red[2 * WW + j][cc * 4 + q] = acc2[j];
      }
      __syncthreads();

      // ---- fused gate epilogue: thread handles 2 rows at its column ----
      {
        const int jp = tid >> 7;  // 0..3 -> rows 2jp, 2jp+1
#pragma unroll
        for (int e = 0; e < 2; ++e) {
          const int j = jp * 2 + e;
          const int4 sg = sseg[j];
          if (s < sg.z) {
            const float4 pr = *(const float4*)&red[0 * WW + j][cc * 4];
            const float4 pz = *(const float4*)&red[1 * WW + j][cc * 4];
            const float4 pn = *(const float4*)&red[2 * WW + j][cc * 4];
            const float sr = pr.x + pr.y + pr.z + pr.w;
            const float sz = pz.x + pz.y + pz.z + pz.w;
            const float sn = pn.x + pn.y + pn.z + pn.w;
            const int orow = (sg.y + s) * NN + sg.x;
            const float* gp = gi + (size_t)orow * GG + col;
            const float ir = gp[0], iz = gp[512], inn = gp[1024];
            const float r = 1.0f / (1.0f + expf(-(ir + sr + bhr)));
            const float z = 1.0f / (1.0f + expf(-(iz + sz + bhz)));
            const float hold = hS[j][col];
            const float nc = tanhf(inn + r * (sn + bhn));
            out[(size_t)orow * HH + col] = (1.0f - z) * nc + z * hold;
          }
        }
      }
      __threadfence();
      __syncthreads();
      if (tid == 0)
        __hip_atomic_fetch_add(&ctr[b * 16], 1, __ATOMIC_RELEASE,
                               __HIP_MEMORY_SCOPE_AGENT);
    }
  }
}

// h_last = out rows [8128..8192) (contiguous), plus hxs_1 passthrough.
__global__ void tail_copy(const float4* __restrict__ src_out,
                          const float4* __restrict__ hxs1,
                          float4* __restrict__ dst) {
  const int i = blockIdx.x * 256 + threadIdx.x;  // 0..16383
  if (i < 8192)
    dst[1048576 + i] = src_out[1040384 + i];  // 8128*512/4 = 1040384
  else
    dst[1048576 + i] = hxs1[i - 8192];
}

extern "C" void kernel_launch(void* const* d_in, const int* in_sizes, int n_in,
                              void* d_out, int out_size, void* d_ws, size_t ws_size,
                              hipStream_t stream) {
  const float* x     = (const float*)d_in[0];
  const float* hxs   = (const float*)d_in[1];
  const float* hxs_1 = (const float*)d_in[2];
  const float* masks = (const float*)d_in[3];
  const float* w_ih  = (const float*)d_in[4];
  const float* w_hh  = (const float*)d_in[5];
  const float* b_ih  = (const float*)d_in[6];
  const float* b_hh  = (const float*)d_in[7];
  float* out = (float*)d_out;
  char* ws = (char*)d_ws;
  if (ws_size < WS_NEEDED) return;

  int* meta   = (int*)(ws + META_OFF);
  int* ctr    = (int*)(ws + CTR_OFF);
  int4* segs  = (int4*)(ws + SEG_OFF);
  int* zRows  = (int*)(ws + ZR_OFF);
  float* gi   = (float*)(ws + GI_OFF);

  build_chains<<<1, 128, 0, stream>>>(masks, meta, ctr, segs, zRows);
  gemm_gi<<<dim3(12, 64), 256, 0, stream>>>(x, w_ih, b_ih, gi);
  heads_ew<<<2048, 256, 0, stream>>>(gi, b_hh, meta, zRows, out);
  gru_chains<<<256, 512, 0, stream>>>(gi, w_hh, b_hh, hxs, out, meta, ctr, segs);
  tail_copy<<<64, 256, 0, stream>>>((const float4*)out, (const float4*)hxs_1,
                                    (float4*)out);
}

// Round 6
// 1118.105 us; speedup vs baseline: 1.3818x; 1.0102x over previous
//
#include <hip/hip_runtime.h>
#include <cmath>

// Problem constants: T=128, N=64, D=512, H=512
#define TT 128
#define NN 64
#define DD 512
#define HH 512
#define GG 1536  // 3*H
#define WW 8     // segments per batch
#define GQ 4     // blocks (col-quarters) per batch
#define NG 64    // static partner groups (256 blocks / GQ)

// ---- workspace layout (bytes) ----
// meta[0]=unused, meta[1]=unused, meta[2]=headCnt, meta[3]=nBatches
#define META_OFF 0
#define CTR_OFF  4096      // int ctr[512*16]  (one counter per 64B line)
#define SEG_OFF  40960     // int4 segs[512*8]
#define ZR_OFF   131072    // int zRows[8192]
#define GI_OFF   4194304   // float gi[8192][1536], 50.3 MB
#define WS_NEEDED (GI_OFF + (size_t)TT * NN * GG * 4)

typedef __attribute__((ext_vector_type(8))) short short8;
typedef __attribute__((ext_vector_type(4))) float f32x4;

__device__ __forceinline__ unsigned short f2bf(float f) {
  union { float f; unsigned u; } c; c.f = f;
  return (unsigned short)((c.u + 0x7fffu + ((c.u >> 16) & 1u)) >> 16);
}

// ---------------------------------------------------------------------------
// Chain builder: mask==0 rows are heads (h_in=0); maximal mask==1 runs are
// chains, counting-sorted by length desc, batched by 8. meta[3] = #batches.
// ctr[] zeroed here (graph-replay safe).
// ---------------------------------------------------------------------------
__global__ void build_chains(const float* __restrict__ masks, int* __restrict__ meta,
                             int* __restrict__ ctr, int4* __restrict__ segs,
                             int* __restrict__ zRows) {
  __shared__ int hist[129];
  __shared__ int offs[129];
  __shared__ int zc;
  __shared__ int nsegS;
  const int tid = threadIdx.x;  // 128
  for (int i = tid; i < 129; i += 128) hist[i] = 0;
  for (int i = tid; i < 512 * 16; i += 128) ctr[i] = 0;
  if (tid == 0) zc = 0;
  __syncthreads();
  if (tid < NN) {
    const int n = tid;
    int run = 0;
    for (int t = 0; t < TT; ++t) {
      const bool m = masks[t * NN + n] != 0.0f;
      if (m) ++run;
      if (!m) {
        atomicAdd(&zc, 1);
        if (run > 0) { atomicAdd(&hist[run], 1); run = 0; }
      } else if (t == TT - 1) {
        atomicAdd(&hist[run], 1);
      }
    }
  }
  __syncthreads();
  if (tid == 0) {
    int acc = 0;
    for (int l = 128; l >= 1; --l) { offs[l] = acc; acc += hist[l]; }
    nsegS = acc;
    meta[2] = zc;
    zc = 0;
  }
  __syncthreads();
  if (tid < NN) {
    const int n = tid;
    int run = 0, tf = 0;
    for (int t = 0; t < TT; ++t) {
      const bool m = masks[t * NN + n] != 0.0f;
      if (m) { if (run == 0) tf = t; ++run; }
      if (!m) {
        const int p = atomicAdd(&zc, 1);
        zRows[p] = t * NN + n;
        if (run > 0) {
          const int pp = atomicAdd(&offs[run], 1);
          segs[pp] = make_int4(n, tf, run, 0);
          run = 0;
        }
      } else if (t == TT - 1) {
        const int pp = atomicAdd(&offs[run], 1);
        segs[pp] = make_int4(n, tf, run, 0);
      }
    }
  }
  __syncthreads();
  const int nseg = nsegS;
  const int nB = (nseg + WW - 1) / WW;
  for (int i = nseg + tid; i < nB * WW; i += 128) segs[i] = make_int4(0, 1, 0, 0);
  if (tid == 0) { meta[0] = 0; meta[3] = nB; }
}

// ---------------------------------------------------------------------------
// gi = x @ w_ih^T + b_ih via bf16 MFMA (fp32 accum, fp32 bias).
// 128x128 tile, 4 waves as 2x2, each wave 64x64 (4x4 fragments of 16x16x32).
// fp32->bf16 RNE conversion fused into LDS staging.
// ---------------------------------------------------------------------------
__global__ __launch_bounds__(256) void gemm_gi(const float* __restrict__ x,
                                               const float* __restrict__ w,
                                               const float* __restrict__ bias,
                                               float* __restrict__ gi) {
  __shared__ __align__(16) short As[128 * 40];
  __shared__ __align__(16) short Bs[128 * 40];
  const int tid = threadIdx.x;
  const int m0 = blockIdx.y * 128, n0 = blockIdx.x * 128;
  const int l = tid & 63, wv = tid >> 6;
  const int wr = wv >> 1, wc = wv & 1;
  const int lr = l & 15, lk = l >> 4;  // fragment row(col) and k-group
  f32x4 acc[4][4];
#pragma unroll
  for (int m = 0; m < 4; ++m)
#pragma unroll
    for (int n = 0; n < 4; ++n) {
      acc[m][n][0] = 0.f; acc[m][n][1] = 0.f;
      acc[m][n][2] = 0.f; acc[m][n][3] = 0.f;
    }
  for (int k0 = 0; k0 < DD; k0 += 32) {
#pragma unroll
    for (int ch = 0; ch < 2; ++ch) {
      const int c = tid + ch * 256;         // 0..511
      const int row = c >> 2, ko = (c & 3) * 8;
      const float* ga = &x[(size_t)(m0 + row) * DD + k0 + ko];
      const float4 a0 = *(const float4*)ga;
      const float4 a1 = *(const float4*)(ga + 4);
      short8 av;
      av[0] = (short)f2bf(a0.x); av[1] = (short)f2bf(a0.y);
      av[2] = (short)f2bf(a0.z); av[3] = (short)f2bf(a0.w);
      av[4] = (short)f2bf(a1.x); av[5] = (short)f2bf(a1.y);
      av[6] = (short)f2bf(a1.z); av[7] = (short)f2bf(a1.w);
      *(short8*)&As[row * 40 + ko] = av;
      const float* gb = &w[(size_t)(n0 + row) * DD + k0 + ko];
      const float4 b0 = *(const float4*)gb;
      const float4 b1 = *(const float4*)(gb + 4);
      short8 bv;
      bv[0] = (short)f2bf(b0.x); bv[1] = (short)f2bf(b0.y);
      bv[2] = (short)f2bf(b0.z); bv[3] = (short)f2bf(b0.w);
      bv[4] = (short)f2bf(b1.x); bv[5] = (short)f2bf(b1.y);
      bv[6] = (short)f2bf(b1.z); bv[7] = (short)f2bf(b1.w);
      *(short8*)&Bs[row * 40 + ko] = bv;
    }
    __syncthreads();
    short8 af[4], bf_[4];
#pragma unroll
    for (int m = 0; m < 4; ++m)
      af[m] = *(const short8*)&As[(wr * 64 + m * 16 + lr) * 40 + lk * 8];
#pragma unroll
    for (int n = 0; n < 4; ++n)
      bf_[n] = *(const short8*)&Bs[(wc * 64 + n * 16 + lr) * 40 + lk * 8];
#pragma unroll
    for (int m = 0; m < 4; ++m)
#pragma unroll
      for (int n = 0; n < 4; ++n)
        acc[m][n] =
            __builtin_amdgcn_mfma_f32_16x16x32_bf16(af[m], bf_[n], acc[m][n], 0, 0, 0);
    __syncthreads();
  }
  // epilogue: C/D layout col=lane&15, row=(lane>>4)*4+reg (m89-verified)
#pragma unroll
  for (int n = 0; n < 4; ++n) {
    const int col = n0 + wc * 64 + n * 16 + lr;
    const float bv = bias[col];
#pragma unroll
    for (int m = 0; m < 4; ++m) {
      const int rbase = m0 + wr * 64 + m * 16 + lk * 4;
#pragma unroll
      for (int j = 0; j < 4; ++j)
        gi[(size_t)(rbase + j) * GG + col] = acc[m][n][j] + bv;
    }
  }
}

// ---------------------------------------------------------------------------
// Head rows (h_in = 0): pure elementwise gates. gh = b_hh.
// ---------------------------------------------------------------------------
__global__ void heads_ew(const float* __restrict__ gi, const float* __restrict__ b_hh,
                         const int* __restrict__ meta, const int* __restrict__ zRows,
                         float* __restrict__ out) {
  const int total = meta[2] * HH;
  for (int idx = blockIdx.x * blockDim.x + threadIdx.x; idx < total;
       idx += gridDim.x * blockDim.x) {
    const int zr = zRows[idx >> 9];
    const int c = idx & 511;
    const float* g = gi + (size_t)zr * GG + c;
    const float r = 1.0f / (1.0f + expf(-(g[0] + b_hh[c])));
    const float z = 1.0f / (1.0f + expf(-(g[512] + b_hh[512 + c])));
    const float nc = tanhf(g[1024] + r * b_hh[1024 + c]);
    out[(size_t)zr * HH + c] = (1.0f - z) * nc;
  }
}

// ---------------------------------------------------------------------------
// Chain kernel, static partner groups. Group g = blocks {g, g+64, g+128,
// g+192} (likely same XCD under round-robin placement — perf heuristic only).
// Pass p: batch p*64 + (p odd ? 63-g : g) (snake). Block quarter gq streams
// its 384 w_hh row-halves (0.75 MB) from L2 per step, computes cols
// [gq*128,(gq+1)*128) for 8 chains.
// CORRECTNESS (Guideline 16): the h payload round-trips through `out` with
// AGENT-scope atomic stores/loads (write-through to / read from the device
// coherence point) — visibility no longer depends on cross-XCD L2 writeback
// timing. Order is provided by the per-batch ctr release/acquire.
// ---------------------------------------------------------------------------
__global__ __launch_bounds__(512) void gru_chains(
    const float* __restrict__ gi, const float* __restrict__ w_hh,
    const float* __restrict__ b_hh, const float* __restrict__ hxs,
    float* __restrict__ out, int* __restrict__ meta, int* __restrict__ ctr,
    const int4* __restrict__ segs) {
  __shared__ __align__(16) float hS[WW][520];       // 16.6 KB staged h rows
  __shared__ __align__(16) float red[3 * WW][516];  // 49.5 KB k-partials
  __shared__ int4 sseg[WW];

  const int tid = threadIdx.x;
  const int cc = tid & 127;   // output column within quarter
  const int q = tid >> 7;     // k-quarter 0..3
  const int g = blockIdx.x & (NG - 1);   // partner group (same XCD likely)
  const int gq = blockIdx.x >> 6;        // col-quarter 0..3
  const int cb = gq * 128;
  const int nB = meta[3];
  const int P = (nB + NG - 1) / NG;

  const int col = cb + cc;
  const float bhr = b_hh[col];
  const float bhz = b_hh[512 + col];
  const float bhn = b_hh[1024 + col];
  const float* w0 = w_hh + (size_t)(col)*DD + q * 128;
  const float* w1 = w_hh + (size_t)(512 + col) * DD + q * 128;
  const float* w2 = w_hh + (size_t)(1024 + col) * DD + q * 128;

  for (int p = 0; p < P; ++p) {
    const int b = p * NG + ((p & 1) ? (NG - 1 - g) : g);
    if (b >= nB) continue;
    __syncthreads();
    if (tid < WW) sseg[tid] = segs[b * WW + tid];
    __syncthreads();
    const int maxlen = sseg[0].z;  // sorted desc -> first is longest

    for (int s = 0; s < maxlen; ++s) {
      if (s > 0) {
        if (tid == 0) {
          while (__hip_atomic_load(&ctr[b * 16], __ATOMIC_ACQUIRE,
                                   __HIP_MEMORY_SCOPE_AGENT) < GQ * s) {
            __builtin_amdgcn_s_sleep(2);
          }
        }
        __syncthreads();
        __threadfence();
      }
      // ---- stage the 8 h rows (512 cols each) into LDS; wave j stages row
      // j via coalesced agent-scope atomic loads (device-coherent point) ----
      {
        const int j = tid >> 6, ll = tid & 63;
        const int4 sg = sseg[j];
        const int r = sg.y - 1 + s;
        const bool act = (s < sg.z);
        const float* hp = act ? ((r >= 0) ? out + (size_t)(r * NN + sg.x) * HH
                                          : hxs + (size_t)sg.x * HH)
                              : out;  // safe dummy
#pragma unroll
        for (int u = 0; u < 8; ++u)
          hS[j][u * 64 + ll] = __hip_atomic_load(
              hp + u * 64 + ll, __ATOMIC_RELAXED, __HIP_MEMORY_SCOPE_AGENT);
      }
      __syncthreads();

      // ---- k-loop: 128 k per thread, 3 gates x 8 rows ----
      float acc0[WW], acc1[WW], acc2[WW];
#pragma unroll
      for (int j = 0; j < WW; ++j) { acc0[j] = 0.f; acc1[j] = 0.f; acc2[j] = 0.f; }
#pragma unroll 2
      for (int k = 0; k < 128; k += 4) {
        const float4 a0 = *(const float4*)(w0 + k);
        const float4 a1 = *(const float4*)(w1 + k);
        const float4 a2 = *(const float4*)(w2 + k);
#pragma unroll
        for (int j = 0; j < WW; ++j) {
          const float4 hv = *(const float4*)&hS[j][q * 128 + k];
          acc0[j] = fmaf(a0.x, hv.x, acc0[j]);
          acc0[j] = fmaf(a0.y, hv.y, acc0[j]);
          acc0[j] = fmaf(a0.z, hv.z, acc0[j]);
          acc0[j] = fmaf(a0.w, hv.w, acc0[j]);
          acc1[j] = fmaf(a1.x, hv.x, acc1[j]);
          acc1[j] = fmaf(a1.y, hv.y, acc1[j]);
          acc1[j] = fmaf(a1.z, hv.z, acc1[j]);
          acc1[j] = fmaf(a1.w, hv.w, acc1[j]);
          acc2[j] = fmaf(a2.x, hv.x, acc2[j]);
          acc2[j] = fmaf(a2.y, hv.y, acc2[j]);
          acc2[j] = fmaf(a2.z, hv.z, acc2[j]);
          acc2[j] = fmaf(a2.w, hv.w, acc2[j]);
        }
      }
      // ---- cross-quarter reduce via LDS ----
#pragma unroll
      for (int j = 0; j < WW; ++j) {
        red[0 * WW + j][cc * 4 + q] = acc0[j];
        red[1 * WW + j][cc * 4 + q] = acc1[j];
        red[2 * WW + j][cc * 4 + q] = acc2[j];
      }
      __syncthreads();

      // ---- fused gate epilogue: thread handles 2 rows at its column ----
      {
        const int jp = tid >> 7;  // 0..3 -> rows 2jp, 2jp+1
#pragma unroll
        for (int e = 0; e < 2; ++e) {
          const int j = jp * 2 + e;
          const int4 sg = sseg[j];
          if (s < sg.z) {
            const float4 pr = *(const float4*)&red[0 * WW + j][cc * 4];
            const float4 pz = *(const float4*)&red[1 * WW + j][cc * 4];
            const float4 pn = *(const float4*)&red[2 * WW + j][cc * 4];
            const float sr = pr.x + pr.y + pr.z + pr.w;
            const float sz = pz.x + pz.y + pz.z + pz.w;
            const float sn = pn.x + pn.y + pn.z + pn.w;
            const int orow = (sg.y + s) * NN + sg.x;
            const float* gp = gi + (size_t)orow * GG + col;
            const float ir = gp[0], iz = gp[512], inn = gp[1024];
            const float r = 1.0f / (1.0f + expf(-(ir + sr + bhr)));
            const float z = 1.0f / (1.0f + expf(-(iz + sz + bhz)));
            const float hold = hS[j][col];
            const float nc = tanhf(inn + r * (sn + bhn));
            __hip_atomic_store(&out[(size_t)orow * HH + col], (1.0f - z) * nc + z * hold,
                               __ATOMIC_RELAXED, __HIP_MEMORY_SCOPE_AGENT);
          }
        }
      }
      __threadfence();
      __syncthreads();
      if (tid == 0)
        __hip_atomic_fetch_add(&ctr[b * 16], 1, __ATOMIC_RELEASE,
                               __HIP_MEMORY_SCOPE_AGENT);
    }
  }
}

// h_last = out rows [8128..8192) (contiguous), plus hxs_1 passthrough.
__global__ void tail_copy(const float4* __restrict__ src_out,
                          const float4* __restrict__ hxs1,
                          float4* __restrict__ dst) {
  const int i = blockIdx.x * 256 + threadIdx.x;  // 0..16383
  if (i < 8192)
    dst[1048576 + i] = src_out[1040384 + i];  // 8128*512/4 = 1040384
  else
    dst[1048576 + i] = hxs1[i - 8192];
}

extern "C" void kernel_launch(void* const* d_in, const int* in_sizes, int n_in,
                              void* d_out, int out_size, void* d_ws, size_t ws_size,
                              hipStream_t stream) {
  const float* x     = (const float*)d_in[0];
  const float* hxs   = (const float*)d_in[1];
  const float* hxs_1 = (const float*)d_in[2];
  const float* masks = (const float*)d_in[3];
  const float* w_ih  = (const float*)d_in[4];
  const float* w_hh  = (const float*)d_in[5];
  const float* b_ih  = (const float*)d_in[6];
  const float* b_hh  = (const float*)d_in[7];
  float* out = (float*)d_out;
  char* ws = (char*)d_ws;
  if (ws_size < WS_NEEDED) return;

  int* meta   = (int*)(ws + META_OFF);
  int* ctr    = (int*)(ws + CTR_OFF);
  int4* segs  = (int4*)(ws + SEG_OFF);
  int* zRows  = (int*)(ws + ZR_OFF);
  float* gi   = (float*)(ws + GI_OFF);

  build_chains<<<1, 128, 0, stream>>>(masks, meta, ctr, segs, zRows);
  gemm_gi<<<dim3(12, 64), 256, 0, stream>>>(x, w_ih, b_ih, gi);
  heads_ew<<<2048, 256, 0, stream>>>(gi, b_hh, meta, zRows, out);
  gru_chains<<<256, 512, 0, stream>>>(gi, w_hh, b_hh, hxs, out, meta, ctr, segs);
  tail_copy<<<64, 256, 0, stream>>>((const float4*)out, (const float4*)hxs_1,
                                    (float4*)out);
}

// Round 7
// 1035.447 us; speedup vs baseline: 1.4921x; 1.0798x over previous
//
#include <hip/hip_runtime.h>
#include <hip/hip_cooperative_groups.h>
#include <cmath>

namespace cg = cooperative_groups;

// Problem constants: T=128, N=64, D=512, H=512
#define TT 128
#define NN 64
#define DD 512
#define HH 512
#define GG 1536  // 3*H

// ---- workspace layout (bytes) ----
// meta[0]=maxlen, meta[2]=headCnt, meta[3]=nseg
#define META_OFF 0
#define ROFF_OFF 256       // int roundCnt[128]
#define SEG_OFF  4096      // int4 cseg[4096] (sorted desc by len)
#define ZR_OFF   69632     // int zRows[8192]
#define WBF_OFF  131072    // bf16 wbf[1536][512], 1.5 MB
#define GI_OFF   4194304   // float gi[8192][1536], 50.3 MB
#define WS_NEEDED (GI_OFF + (size_t)TT * NN * GG * 4)

typedef __attribute__((ext_vector_type(8))) short short8;
typedef __attribute__((ext_vector_type(4))) float f32x4;
typedef __attribute__((ext_vector_type(4))) unsigned short ushort4_t;

__device__ __forceinline__ unsigned short f2bf(float f) {
  union { float f; unsigned u; } c; c.f = f;
  return (unsigned short)((c.u + 0x7fffu + ((c.u >> 16) & 1u)) >> 16);
}

// ---------------------------------------------------------------------------
// Chain builder: mask==0 rows are heads (h_in=0, elementwise); maximal
// mask==1 runs are chains, counting-sorted desc by length into cseg.
// roundCnt[s] = #chains with len >= s+1  ->  round s's active chains are
// EXACTLY ranks [0, roundCnt[s]) (contiguous prefix).
// ---------------------------------------------------------------------------
__global__ void build_chains(const float* __restrict__ masks, int* __restrict__ meta,
                             int* __restrict__ roundCnt, int4* __restrict__ cseg,
                             int* __restrict__ zRows) {
  __shared__ int hist[130];
  __shared__ int offs[130];
  __shared__ int zc;
  const int tid = threadIdx.x;  // 128
  for (int i = tid; i < 130; i += 128) hist[i] = 0;
  if (tid == 0) zc = 0;
  __syncthreads();
  if (tid < NN) {
    const int n = tid;
    int run = 0;
    for (int t = 0; t < TT; ++t) {
      const bool m = masks[t * NN + n] != 0.0f;
      if (m) ++run;
      if (!m) {
        atomicAdd(&zc, 1);
        if (run > 0) { atomicAdd(&hist[run], 1); run = 0; }
      } else if (t == TT - 1) {
        atomicAdd(&hist[run], 1);
      }
    }
  }
  __syncthreads();
  if (tid == 0) {
    int acc = 0, maxl = 0;
    for (int l = 128; l >= 1; --l) {
      offs[l] = acc;
      acc += hist[l];
      if (hist[l] > 0 && maxl == 0) maxl = l;
    }
    int suf = 0;
    for (int l = 128; l >= 1; --l) { suf += hist[l]; roundCnt[l - 1] = suf; }
    meta[0] = maxl;
    meta[2] = zc;
    meta[3] = acc;
    zc = 0;
  }
  __syncthreads();
  if (tid < NN) {
    const int n = tid;
    int run = 0, tf = 0;
    for (int t = 0; t < TT; ++t) {
      const bool m = masks[t * NN + n] != 0.0f;
      if (m) { if (run == 0) tf = t; ++run; }
      if (!m) {
        const int p = atomicAdd(&zc, 1);
        zRows[p] = t * NN + n;
        if (run > 0) {
          const int pp = atomicAdd(&offs[run], 1);
          cseg[pp] = make_int4(n, tf, run, 0);
          run = 0;
        }
      } else if (t == TT - 1) {
        const int pp = atomicAdd(&offs[run], 1);
        cseg[pp] = make_int4(n, tf, run, 0);
      }
    }
  }
}

// w_hh f32[1536][512] -> bf16 (halves the recurrent weight stream; MFMA input)
__global__ void conv_whh(const float* __restrict__ w, unsigned short* __restrict__ wbf) {
  const int i = blockIdx.x * 256 + threadIdx.x;  // float4 units, 196608 total
  const float4 v = ((const float4*)w)[i];
  ushort4_t p;
  p.x = f2bf(v.x); p.y = f2bf(v.y); p.z = f2bf(v.z); p.w = f2bf(v.w);
  ((ushort4_t*)wbf)[i] = p;
}

// ---------------------------------------------------------------------------
// gi = x @ w_ih^T + b_ih via bf16 MFMA (validated R6, absmax 0.0156).
// ---------------------------------------------------------------------------
__global__ __launch_bounds__(256) void gemm_gi(const float* __restrict__ x,
                                               const float* __restrict__ w,
                                               const float* __restrict__ bias,
                                               float* __restrict__ gi) {
  __shared__ __align__(16) short As[128 * 40];
  __shared__ __align__(16) short Bs[128 * 40];
  const int tid = threadIdx.x;
  const int m0 = blockIdx.y * 128, n0 = blockIdx.x * 128;
  const int l = tid & 63, wv = tid >> 6;
  const int wr = wv >> 1, wc = wv & 1;
  const int lr = l & 15, lk = l >> 4;
  f32x4 acc[4][4];
#pragma unroll
  for (int m = 0; m < 4; ++m)
#pragma unroll
    for (int n = 0; n < 4; ++n) {
      acc[m][n][0] = 0.f; acc[m][n][1] = 0.f;
      acc[m][n][2] = 0.f; acc[m][n][3] = 0.f;
    }
  for (int k0 = 0; k0 < DD; k0 += 32) {
#pragma unroll
    for (int ch = 0; ch < 2; ++ch) {
      const int c = tid + ch * 256;
      const int row = c >> 2, ko = (c & 3) * 8;
      const float* ga = &x[(size_t)(m0 + row) * DD + k0 + ko];
      const float4 a0 = *(const float4*)ga;
      const float4 a1 = *(const float4*)(ga + 4);
      short8 av;
      av[0] = (short)f2bf(a0.x); av[1] = (short)f2bf(a0.y);
      av[2] = (short)f2bf(a0.z); av[3] = (short)f2bf(a0.w);
      av[4] = (short)f2bf(a1.x); av[5] = (short)f2bf(a1.y);
      av[6] = (short)f2bf(a1.z); av[7] = (short)f2bf(a1.w);
      *(short8*)&As[row * 40 + ko] = av;
      const float* gb = &w[(size_t)(n0 + row) * DD + k0 + ko];
      const float4 b0 = *(const float4*)gb;
      const float4 b1 = *(const float4*)(gb + 4);
      short8 bv;
      bv[0] = (short)f2bf(b0.x); bv[1] = (short)f2bf(b0.y);
      bv[2] = (short)f2bf(b0.z); bv[3] = (short)f2bf(b0.w);
      bv[4] = (short)f2bf(b1.x); bv[5] = (short)f2bf(b1.y);
      bv[6] = (short)f2bf(b1.z); bv[7] = (short)f2bf(b1.w);
      *(short8*)&Bs[row * 40 + ko] = bv;
    }
    __syncthreads();
    short8 af[4], bf_[4];
#pragma unroll
    for (int m = 0; m < 4; ++m)
      af[m] = *(const short8*)&As[(wr * 64 + m * 16 + lr) * 40 + lk * 8];
#pragma unroll
    for (int n = 0; n < 4; ++n)
      bf_[n] = *(const short8*)&Bs[(wc * 64 + n * 16 + lr) * 40 + lk * 8];
#pragma unroll
    for (int m = 0; m < 4; ++m)
#pragma unroll
      for (int n = 0; n < 4; ++n)
        acc[m][n] =
            __builtin_amdgcn_mfma_f32_16x16x32_bf16(af[m], bf_[n], acc[m][n], 0, 0, 0);
    __syncthreads();
  }
#pragma unroll
  for (int n = 0; n < 4; ++n) {
    const int col = n0 + wc * 64 + n * 16 + lr;
    const float bv = bias[col];
#pragma unroll
    for (int m = 0; m < 4; ++m) {
      const int rbase = m0 + wr * 64 + m * 16 + lk * 4;
#pragma unroll
      for (int j = 0; j < 4; ++j)
        gi[(size_t)(rbase + j) * GG + col] = acc[m][n][j] + bv;
    }
  }
}

// Head rows (h_in = 0): pure elementwise gates (gh = b_hh, no GEMM).
__global__ void heads_ew(const float* __restrict__ gi, const float* __restrict__ b_hh,
                         const int* __restrict__ meta, const int* __restrict__ zRows,
                         float* __restrict__ out) {
  const int total = meta[2] * HH;
  for (int idx = blockIdx.x * blockDim.x + threadIdx.x; idx < total;
       idx += gridDim.x * blockDim.x) {
    const int zr = zRows[idx >> 9];
    const int c = idx & 511;
    const float* g = gi + (size_t)zr * GG + c;
    const float r = 1.0f / (1.0f + expf(-(g[0] + b_hh[c])));
    const float z = 1.0f / (1.0f + expf(-(g[512] + b_hh[512 + c])));
    const float nc = tanhf(g[1024] + r * b_hh[1024 + c]);
    out[(size_t)zr * HH + c] = (1.0f - z) * nc;
  }
}

// ---------------------------------------------------------------------------
// Round-synchronized recurrence as per-round batched MFMA GEMM.
// Round s: chains [0, roundCnt[s]) each need gh = h_{s-1} @ w_hh^T for their
// step-s row. Tiles of 32 chains x 64 h-cols x 3 gates; grid-strided over
// 512 cooperative blocks; grid.sync() between rounds (~13 total).
// A (h rows, gathered from out/hxs) -> bf16 LDS; B (w_hh bf16) streamed
// from L2 per k-chunk with 1-deep register prefetch; fused gate epilogue
// (h_old read in f32 from the source row — no bf16 error on the carry).
// ---------------------------------------------------------------------------
#define MT 32    // chains per tile
#define CT 64    // h-cols per tile (x3 gates)
#define ASTR 536 // LDS row stride in bf16 (1072 B: 16B-aligned, bank-spread)

__global__ __launch_bounds__(256, 2) void gru_rounds2(
    const float* __restrict__ gi, const unsigned short* __restrict__ wbf,
    const float* __restrict__ b_hh, const float* __restrict__ hxs,
    float* __restrict__ out, const int* __restrict__ meta,
    const int* __restrict__ roundCnt, const int4* __restrict__ cseg) {
  __shared__ __align__(16) unsigned short As[MT * ASTR];  // 33.5 KB
  __shared__ int4 sseg[MT];
  __shared__ const float* sptr[MT];
  cg::grid_group grid = cg::this_grid();
  const int tid = threadIdx.x;
  const int wv = tid >> 6, l = tid & 63;
  const int lr = l & 15, lk = l >> 4;
  const int maxlen = meta[0];

  for (int s = 0; s < maxlen; ++s) {
    const int acnt = roundCnt[s];
    const int ntiles = ((acnt + MT - 1) / MT) * (HH / CT);
    for (int tile = blockIdx.x; tile < ntiles; tile += gridDim.x) {
      const int rt = tile >> 3, ct = tile & 7;
      const int rowbase = rt * MT, ct0 = ct * CT;
      const int rows = min(MT, acnt - rowbase);
      __syncthreads();  // protect As/sseg reuse from previous tile
      if (tid < MT) {
        int4 sg = make_int4(0, 0, 0, 0);
        const float* hp = hxs;
        if (tid < rows) {
          sg = cseg[rowbase + tid];
          hp = (s == 0) ? ((sg.y == 0) ? hxs + (size_t)sg.x * HH
                                       : out + (size_t)((sg.y - 1) * NN + sg.x) * HH)
                        : out + (size_t)((sg.y + s - 1) * NN + sg.x) * HH;
        }
        sseg[tid] = sg;
        sptr[tid] = hp;
      }
      __syncthreads();
      // ---- stage A: 32 h-rows f32 -> bf16 LDS (8 threads/row) ----
      {
        const int r = tid >> 3, c8 = tid & 7;
        const float* hp = sptr[r];
#pragma unroll
        for (int i = 0; i < 16; ++i) {
          const int f4 = c8 + (i << 3);  // float4 index 0..127
          const float4 v = ((const float4*)hp)[f4];
          ushort4_t pv;
          pv.x = f2bf(v.x); pv.y = f2bf(v.y); pv.z = f2bf(v.z); pv.w = f2bf(v.w);
          *(ushort4_t*)&As[r * ASTR + f4 * 4] = pv;
        }
      }
      __syncthreads();
      // ---- K-loop: B streamed from L2, 1-deep prefetch; 6 MFMA/chunk ----
      const int wcol = ct0 + wv * 16 + lr;  // this lane's output h-col
      const unsigned short* bp0 = wbf + (size_t)wcol * DD + lk * 8;
      const unsigned short* bp1 = wbf + (size_t)(512 + wcol) * DD + lk * 8;
      const unsigned short* bp2 = wbf + (size_t)(1024 + wcol) * DD + lk * 8;
      f32x4 acc[6];
#pragma unroll
      for (int i = 0; i < 6; ++i) {
        acc[i][0] = 0.f; acc[i][1] = 0.f; acc[i][2] = 0.f; acc[i][3] = 0.f;
      }
      short8 b0 = *(const short8*)bp0;
      short8 b1 = *(const short8*)bp1;
      short8 b2 = *(const short8*)bp2;
#pragma unroll
      for (int kc = 0; kc < 16; ++kc) {
        short8 n0, n1, n2;
        if (kc < 15) {
          n0 = *(const short8*)(bp0 + (kc + 1) * 32);
          n1 = *(const short8*)(bp1 + (kc + 1) * 32);
          n2 = *(const short8*)(bp2 + (kc + 1) * 32);
        }
        const short8 a0 = *(const short8*)&As[lr * ASTR + kc * 32 + lk * 8];
        const short8 a1 = *(const short8*)&As[(16 + lr) * ASTR + kc * 32 + lk * 8];
        acc[0] = __builtin_amdgcn_mfma_f32_16x16x32_bf16(a0, b0, acc[0], 0, 0, 0);
        acc[1] = __builtin_amdgcn_mfma_f32_16x16x32_bf16(a0, b1, acc[1], 0, 0, 0);
        acc[2] = __builtin_amdgcn_mfma_f32_16x16x32_bf16(a0, b2, acc[2], 0, 0, 0);
        acc[3] = __builtin_amdgcn_mfma_f32_16x16x32_bf16(a1, b0, acc[3], 0, 0, 0);
        acc[4] = __builtin_amdgcn_mfma_f32_16x16x32_bf16(a1, b1, acc[4], 0, 0, 0);
        acc[5] = __builtin_amdgcn_mfma_f32_16x16x32_bf16(a1, b2, acc[5], 0, 0, 0);
        if (kc < 15) { b0 = n0; b1 = n1; b2 = n2; }
      }
      // ---- fused gate epilogue (C/D layout: col=lane&15, row=lk*4+j) ----
      const float bhr = b_hh[wcol];
      const float bhz = b_hh[512 + wcol];
      const float bhn = b_hh[1024 + wcol];
#pragma unroll
      for (int m = 0; m < 2; ++m) {
#pragma unroll
        for (int j = 0; j < 4; ++j) {
          const int lrow = m * 16 + lk * 4 + j;
          if (lrow < rows) {
            const int4 sg = sseg[lrow];
            const int orow = (sg.y + s) * NN + sg.x;
            const float* gp = gi + (size_t)orow * GG + wcol;
            const float hold = sptr[lrow][wcol];
            const float r = 1.0f / (1.0f + expf(-(gp[0] + acc[m * 3 + 0][j] + bhr)));
            const float z = 1.0f / (1.0f + expf(-(gp[512] + acc[m * 3 + 1][j] + bhz)));
            const float nc = tanhf(gp[1024] + r * (acc[m * 3 + 2][j] + bhn));
            out[(size_t)orow * HH + wcol] = (1.0f - z) * nc + z * hold;
          }
        }
      }
    }
    grid.sync();
  }
}

// h_last = out rows [8128..8192), plus hxs_1 passthrough.
__global__ void tail_copy(const float4* __restrict__ src_out,
                          const float4* __restrict__ hxs1,
                          float4* __restrict__ dst) {
  const int i = blockIdx.x * 256 + threadIdx.x;  // 0..16383
  if (i < 8192)
    dst[1048576 + i] = src_out[1040384 + i];  // 8128*512/4
  else
    dst[1048576 + i] = hxs1[i - 8192];
}

extern "C" void kernel_launch(void* const* d_in, const int* in_sizes, int n_in,
                              void* d_out, int out_size, void* d_ws, size_t ws_size,
                              hipStream_t stream) {
  const float* x     = (const float*)d_in[0];
  const float* hxs   = (const float*)d_in[1];
  const float* hxs_1 = (const float*)d_in[2];
  const float* masks = (const float*)d_in[3];
  const float* w_ih  = (const float*)d_in[4];
  const float* w_hh  = (const float*)d_in[5];
  const float* b_ih  = (const float*)d_in[6];
  const float* b_hh  = (const float*)d_in[7];
  float* out = (float*)d_out;
  char* ws = (char*)d_ws;
  if (ws_size < WS_NEEDED) return;

  int* meta          = (int*)(ws + META_OFF);
  int* roundCnt      = (int*)(ws + ROFF_OFF);
  int4* cseg         = (int4*)(ws + SEG_OFF);
  int* zRows         = (int*)(ws + ZR_OFF);
  unsigned short* wbf = (unsigned short*)(ws + WBF_OFF);
  float* gi          = (float*)(ws + GI_OFF);

  build_chains<<<1, 128, 0, stream>>>(masks, meta, roundCnt, cseg, zRows);
  conv_whh<<<768, 256, 0, stream>>>(w_hh, wbf);
  gemm_gi<<<dim3(12, 64), 256, 0, stream>>>(x, w_ih, b_ih, gi);
  heads_ew<<<2048, 256, 0, stream>>>(gi, b_hh, meta, zRows, out);

  const float* gi_c = gi;
  const unsigned short* wbf_c = wbf;
  const int* meta_c = meta;
  const int* roundCnt_c = roundCnt;
  const int4* cseg_c = cseg;
  void* args[] = {(void*)&gi_c,   (void*)&wbf_c,      (void*)&b_hh,
                  (void*)&hxs,    (void*)&out,        (void*)&meta_c,
                  (void*)&roundCnt_c, (void*)&cseg_c};
  hipLaunchCooperativeKernel((const void*)gru_rounds2, dim3(512), dim3(256), args, 0,
                             stream);
  tail_copy<<<64, 256, 0, stream>>>((const float4*)out, (const float4*)hxs_1,
                                    (float4*)out);
}